// Round 1
// 192.964 us; speedup vs baseline: 1.0464x; 1.0464x over previous
//
#include <hip/hip_runtime.h>
#include <stdint.h>

// ---------------- modular arithmetic ----------------
static constexpr uint32_t P = 2013265921u;         // 15*2^27 + 1
static constexpr int      LOGM = 11;               // per-block DFT size 2048
static constexpr int      MSZ  = 1 << LOGM;
static constexpr int      NCOL = 2;                // matrix columns per block (each el = uint4 = 4 batch cols)

__host__ __device__ constexpr uint32_t neg_pinv32() {
    uint32_t x = 1u;
    for (int i = 0; i < 5; ++i) x *= 2u - P * x;
    return 0u - x;
}
static constexpr uint32_t NEG_PINV = neg_pinv32();
static constexpr uint32_t R1 = (uint32_t)(((uint64_t)1 << 32) % P);
static constexpr uint32_t R2 = (uint32_t)(((uint64_t)R1 * R1) % P);

// Montgomery (R=2^32). mont_mul(plain, Mont(w)) = plain*w  — used for the
// epilogue twiddle chains and the 5 non-trivial phase-0 butterflies.
__device__ __forceinline__ uint32_t mont_mul(uint32_t a, uint32_t b) {
    uint32_t tlo = a * b;
    uint32_t thi = __umulhi(a, b);
    uint32_t m   = tlo * NEG_PINV;
    uint32_t r   = thi + __umulhi(m, P) + (tlo != 0u);   // r < 2P
    uint32_t s   = r - P;
    return s < r ? s : r;
}
__device__ __forceinline__ uint32_t to_mont(uint32_t a) { return mont_mul(a, R2); }

// Shoup mult by precomputed (w, w'=floor(w*2^32/P)): 4 ops + 2-op reduce.
__device__ __forceinline__ uint32_t shoup_mul(uint32_t w, uint32_t wp, uint32_t x) {
    uint32_t q = __umulhi(wp, x);
    uint32_t t = w * x - q * P;          // exact: t in [0, 2P) < 2^32
    uint32_t s = t - P;
    return s < t ? s : t;
}
__device__ __forceinline__ uint32_t add_p(uint32_t a, uint32_t b) {
    uint32_t r = a + b, s = r - P; return s < r ? s : r;
}
__device__ __forceinline__ uint32_t sub_p(uint32_t a, uint32_t b) {
    uint32_t r = a - b, s = r + P; return s < r ? s : r;
}
__device__ __forceinline__ uint4 mm4(uint32_t w, uint4 v) {   // Montgomery x4
    return make_uint4(mont_mul(w, v.x), mont_mul(w, v.y),
                      mont_mul(w, v.z), mont_mul(w, v.w));
}
// butterfly variants (all keep values canonical [0,P))
__device__ __forceinline__ void bf4_sh(uint4& L, uint4& H, uint2 w) {
    uint4 t = make_uint4(shoup_mul(w.x, w.y, H.x), shoup_mul(w.x, w.y, H.y),
                         shoup_mul(w.x, w.y, H.z), shoup_mul(w.x, w.y, H.w));
    uint4 l = L;
    L = make_uint4(add_p(l.x, t.x), add_p(l.y, t.y), add_p(l.z, t.z), add_p(l.w, t.w));
    H = make_uint4(sub_p(l.x, t.x), sub_p(l.y, t.y), sub_p(l.z, t.z), sub_p(l.w, t.w));
}
__device__ __forceinline__ void bf4_mont(uint4& L, uint4& H, uint32_t wm) {
    uint4 t = mm4(wm, H);
    uint4 l = L;
    L = make_uint4(add_p(l.x, t.x), add_p(l.y, t.y), add_p(l.z, t.z), add_p(l.w, t.w));
    H = make_uint4(sub_p(l.x, t.x), sub_p(l.y, t.y), sub_p(l.z, t.z), sub_p(l.w, t.w));
}
__device__ __forceinline__ void bf4_triv(uint4& L, uint4& H) {   // w == 1
    uint4 l = L, h = H;
    L = make_uint4(add_p(l.x, h.x), add_p(l.y, h.y), add_p(l.z, h.z), add_p(l.w, h.w));
    H = make_uint4(sub_p(l.x, h.x), sub_p(l.y, h.y), sub_p(l.z, h.z), sub_p(l.w, h.w));
}

// LDS element swizzle: conflict-free for strides 1/8/64/512.
// With 2 columns packed in bit0, bank-quad = (2*g_sw + c4) mod 8 stays balanced
// for every phase's per-wave access set (stride-8, {1 within 8, jump 64}, stride-1).
__device__ __forceinline__ int g_sw(int el) {
    return el ^ (((el >> 3) ^ (el >> 6)) & 7);
}
__device__ __forceinline__ int fidx(int el, int c4) { return (g_sw(el) << 1) | c4; }

// 3 DIT stages (radix-8) with Shoup twiddles (phases 1-2).
__device__ __forceinline__ void radix8_sh(uint4 x[8],
        uint2 ta, uint2 tb0, uint2 tb1,
        uint2 tc0, uint2 tc1, uint2 tc2, uint2 tc3) {
    bf4_sh(x[0], x[1], ta);  bf4_sh(x[2], x[3], ta);
    bf4_sh(x[4], x[5], ta);  bf4_sh(x[6], x[7], ta);
    bf4_sh(x[0], x[2], tb0); bf4_sh(x[1], x[3], tb1);
    bf4_sh(x[4], x[6], tb0); bf4_sh(x[5], x[7], tb1);
    bf4_sh(x[0], x[4], tc0); bf4_sh(x[1], x[5], tc1);
    bf4_sh(x[2], x[6], tc2); bf4_sh(x[3], x[7], tc3);
}

// One block = 512 threads = one 2048-pt inverse DFT over 2 adjacent matrix
// columns (each element uint4 = 4 batch columns).  c4 = t&1 (global col
// c = 2*grp + c4), sub = t>>1 owns 8 elements.  LDS = 64 KiB buf + ~16 KiB
// stab = 81912 B <= 80 KiB  ->  2 independent blocks/CU (vs 1 before):
// barrier drains and gather latency of one block overlap the other's VALU.
template <bool PASS2>
__global__ __launch_bounds__(512, 4) void intt_pass(
        const uint4* __restrict__ src, uint4* __restrict__ dst,
        const uint32_t* __restrict__ tw,
        const uint32_t* __restrict__ ninv_p)
{
    __shared__ uint4 buf[MSZ * NCOL];   // 64 KiB
    __shared__ uint2 stab[2047];        // 16376 B (w, w_shoup); stage s at 2^(s-1)-1

    const int      t   = threadIdx.x;
    const int      c4  = t & 1;
    const int      sub = t >> 1;           // [0,256)
    const uint32_t bid = blockIdx.x;
    // XCD swizzle for 1024 blocks: XCD k gets grp [k*128,(k+1)*128); the two
    // sibling blocks sharing a 64B line (grp 2g/2g+1) are 8 bids apart -> same XCD.
    const uint32_t grp = ((bid & 7u) << 7) | (bid >> 3);
    const uint32_t c   = (grp << 1) | (uint32_t)c4;        // global matrix column

    // stage-twiddle table build (4 entries/thread): plain w + Shoup companion.
    // stab[2^(s-1)-1 + j] = W^(j*2^(11-s)), W = w^2048 -> tw[j << (21-(s-1))].
    uint32_t wv[4]; int ev[4];
#pragma unroll
    for (int q = 0; q < 4; ++q) {
        int e = t + (q << 9);
        ev[q] = e;
        if (e < 2047) {
            uint32_t ep1 = (uint32_t)e + 1u;
            int sm1 = 31 - __clz((int)ep1);
            uint32_t j = ep1 - (1u << sm1);
            wv[q] = tw[j << (21 - sm1)];
        }
    }

    // global gather, bit-reversal folded in: el = 8*sub+m <- row rev11(el)
    const uint32_t r8 = __brev((uint32_t)sub) >> 24;
    uint4 x[8];
#pragma unroll
    for (int m = 0; m < 8; ++m) {
        uint32_t r3 = __brev((uint32_t)m) >> 29;
        x[m] = src[((r3 << 8) | r8) * (uint32_t)MSZ + c];
    }

    // finish stab (64-bit div overlaps the gather latency)
#pragma unroll
    for (int q = 0; q < 4; ++q) {
        if (ev[q] < 2047) {
            uint32_t w  = wv[q];
            uint32_t wp = (uint32_t)((((uint64_t)w) << 32) / P);
            stab[ev[q]] = make_uint2(w, wp);
        }
    }

    // phase-0 non-trivial twiddles (uniform): u1=W^512, u2=W^256, u3=W^768
    const uint32_t u1 = to_mont(tw[1u << 20]);
    const uint32_t u2 = to_mont(tw[1u << 19]);
    const uint32_t u3 = to_mont(tw[3u << 19]);

    // ---- phase 0: stages 1-3, j=0 group (7 of 12 butterflies are w=1) ----
    bf4_triv(x[0], x[1]);  bf4_triv(x[2], x[3]);
    bf4_triv(x[4], x[5]);  bf4_triv(x[6], x[7]);
    bf4_triv(x[0], x[2]);  bf4_mont(x[1], x[3], u1);
    bf4_triv(x[4], x[6]);  bf4_mont(x[5], x[7], u1);
    bf4_triv(x[0], x[4]);  bf4_mont(x[1], x[5], u2);
    bf4_mont(x[2], x[6], u1); bf4_mont(x[3], x[7], u3);
#pragma unroll
    for (int m = 0; m < 8; ++m) buf[fidx(8 * sub + m, c4)] = x[m];
    __syncthreads();   // covers stab AND phase-0 buf

    // ---- phase 1: stages 4-6 (element stride 8) ----
    {
        const int L = sub & 7, hi = sub >> 3;
        const int base = (hi << 6) | L;
#pragma unroll
        for (int m = 0; m < 8; ++m) x[m] = buf[fidx(base | (m << 3), c4)];
        radix8_sh(x, stab[7 + L], stab[15 + L], stab[23 + L],
                     stab[31 + L], stab[39 + L], stab[47 + L], stab[55 + L]);
#pragma unroll
        for (int m = 0; m < 8; ++m) buf[fidx(base | (m << 3), c4)] = x[m];
    }
    __syncthreads();

    // ---- phase 2: stages 7-9 (element stride 64) ----
    {
        const int L = sub & 63, hi = sub >> 6;
        const int base = (hi << 9) | L;
#pragma unroll
        for (int m = 0; m < 8; ++m) x[m] = buf[fidx(base | (m << 6), c4)];
        radix8_sh(x, stab[63 + L], stab[127 + L], stab[191 + L],
                     stab[255 + L], stab[319 + L], stab[383 + L], stab[447 + L]);
#pragma unroll
        for (int m = 0; m < 8; ++m) buf[fidx(base | (m << 6), c4)] = x[m];
    }
    __syncthreads();

    // ---- phase 3: stages 10-11 (stride 512) + epilogue ----
    uint32_t nm = 0u, s256 = 0u, step512 = 0u, tm0 = 0u;
    if (PASS2) {
        nm = to_mont(*ninv_p);
    } else {
        s256    = to_mont(tw[c << 8]);              // Mont(w^(256c))
        step512 = mont_mul(s256, s256);             // Mont(w^(512c))
        tm0     = to_mont(tw[c * (uint32_t)sub]);   // Mont(w^(c*sub)), exp<2^19
    }
#pragma unroll
    for (int gg = 0; gg < 2; ++gg) {
        const int lo = sub + (gg << 8);             // [0,512)
        uint4 y[4];
#pragma unroll
        for (int m = 0; m < 4; ++m) y[m] = buf[fidx(lo | (m << 9), c4)];
        const uint2 t10  = stab[511 + lo];
        const uint2 t110 = stab[1023 + lo];
        const uint2 t111 = stab[1535 + lo];
        bf4_sh(y[0], y[1], t10);  bf4_sh(y[2], y[3], t10);
        bf4_sh(y[0], y[2], t110); bf4_sh(y[1], y[3], t111);

        if (!PASS2) {
            uint32_t tm = tm0;                      // Mont(w^(c*lo))
#pragma unroll
            for (int m = 0; m < 4; ++m) {
                dst[c * (uint32_t)MSZ + (uint32_t)((m << 9) | lo)] = mm4(tm, y[m]);
                tm = mont_mul(tm, step512);
            }
            tm0 = mont_mul(tm0, s256);              // advance lo by 256
        } else {
#pragma unroll
            for (int m = 0; m < 4; ++m)
                dst[(uint32_t)((m << 9) | lo) * (uint32_t)MSZ + c] = mm4(nm, y[m]);
        }
    }
}

// ------------------------------- launch ------------------------------------
extern "C" void kernel_launch(void* const* d_in, const int* in_sizes, int n_in,
                              void* d_out, int out_size, void* d_ws, size_t ws_size,
                              hipStream_t stream)
{
    const uint4*    x    = (const uint4*)d_in[0];      // (N, 4) int32 rows
    const uint32_t* tw   = (const uint32_t*)d_in[1];   // w^k, k < 2^21
    const uint32_t* ninv = (const uint32_t*)d_in[2];
    uint4*          out  = (uint4*)d_out;

    intt_pass<false><<<dim3(1024), dim3(512), 0, stream>>>(x, out, tw, ninv);
    intt_pass<true ><<<dim3(1024), dim3(512), 0, stream>>>(out, out, tw, ninv);
}